// Round 18
// baseline (76.625 us; speedup 1.0000x reference)
//
#include <hip/hip_runtime.h>
#include <hip/hip_bf16.h>

#define B_ROWS 4096
#define N2 8192
#define DD 512
#define NBLK 1056  // sum over P=0..63 of ceil((128-2P)/4)  (chunks of 256 cols)

typedef __attribute__((ext_vector_type(4))) float float4v;
typedef __attribute__((ext_vector_type(2))) long long2v;

// ---------- normalize + targets + rowsum-zero, one wave per row-pair ----------
// Outputs zn as fp8 e4m3 (OCP), 512 B per row.
__global__ __launch_bounds__(256) void k_norm_tgt(const float* __restrict__ f1,
                                                  const float* __restrict__ f2,
                                                  unsigned char* __restrict__ zn8,
                                                  float* __restrict__ tpart,
                                                  float* __restrict__ rowsum) {
  int w = threadIdx.x >> 6, lane = threadIdx.x & 63;
  int j = blockIdx.x * 4 + w;  // pair index 0..4095
  const float4* s1 = (const float4*)(f1 + (size_t)j * DD);
  const float4* s2 = (const float4*)(f2 + (size_t)j * DD);
  float4 a0 = s1[lane * 2], a1 = s1[lane * 2 + 1];
  float4 b0 = s2[lane * 2], b1 = s2[lane * 2 + 1];
  float ss1 = a0.x * a0.x + a0.y * a0.y + a0.z * a0.z + a0.w * a0.w +
              a1.x * a1.x + a1.y * a1.y + a1.z * a1.z + a1.w * a1.w;
  float ss2 = b0.x * b0.x + b0.y * b0.y + b0.z * b0.z + b0.w * b0.w +
              b1.x * b1.x + b1.y * b1.y + b1.z * b1.z + b1.w * b1.w;
  float ab = a0.x * b0.x + a0.y * b0.y + a0.z * b0.z + a0.w * b0.w +
             a1.x * b1.x + a1.y * b1.y + a1.z * b1.z + a1.w * b1.w;
#pragma unroll
  for (int o = 1; o < 64; o <<= 1) {
    ss1 += __shfl_xor(ss1, o, 64);
    ss2 += __shfl_xor(ss2, o, 64);
    ab += __shfl_xor(ab, o, 64);
  }
  float inv1 = 1.0f / fmaxf(sqrtf(ss1), 1e-8f);
  float inv2 = 1.0f / fmaxf(sqrtf(ss2), 1e-8f);

  uint2 q;
  int lo = __builtin_amdgcn_cvt_pk_fp8_f32(a0.x * inv1, a0.y * inv1, 0, false);
  lo = __builtin_amdgcn_cvt_pk_fp8_f32(a0.z * inv1, a0.w * inv1, lo, true);
  q.x = (unsigned int)lo;
  lo = __builtin_amdgcn_cvt_pk_fp8_f32(a1.x * inv1, a1.y * inv1, 0, false);
  lo = __builtin_amdgcn_cvt_pk_fp8_f32(a1.z * inv1, a1.w * inv1, lo, true);
  q.y = (unsigned int)lo;
  ((uint2*)(zn8 + (size_t)j * DD))[lane] = q;

  lo = __builtin_amdgcn_cvt_pk_fp8_f32(b0.x * inv2, b0.y * inv2, 0, false);
  lo = __builtin_amdgcn_cvt_pk_fp8_f32(b0.z * inv2, b0.w * inv2, lo, true);
  q.x = (unsigned int)lo;
  lo = __builtin_amdgcn_cvt_pk_fp8_f32(b1.x * inv2, b1.y * inv2, 0, false);
  lo = __builtin_amdgcn_cvt_pk_fp8_f32(b1.z * inv2, b1.w * inv2, lo, true);
  q.y = (unsigned int)lo;
  ((uint2*)(zn8 + (size_t)(B_ROWS + j) * DD))[lane] = q;

  if (lane == 0) tpart[j] = 2.0f + 2.0f * ab * inv1 * inv2;  // fp32-exact target terms
  if (threadIdx.x < 8) rowsum[blockIdx.x * 8 + threadIdx.x] = 0.f;  // 1024*8 = 8192
}

// ---------- main: persistent-A fp8 GEMM + exp-rowsum ----------
// Block = 4 waves, 128 A-rows direct global->regs. 8 B-panels of 32 cols x
// 512 K in a 2x16KB LDS double buffer: STAGE(t+1) at loop top, counted
// vmcnt(4), raw barriers. 33.8KB LDS + ~100 VGPR -> 4 blocks/CU: independent
// block phases overlap MFMA (one block) with exp2/VALU epilogue (another).
// Bands P (128 rows), chunks of 256 cols; mirror col-sums for 32-col tiles
// with index J >= 4P+4 (strictly above the 256-wide diagonal block).
__global__ __launch_bounds__(256, 4) void k_gemm_expsum(const unsigned char* __restrict__ zn8,
                                                        float* __restrict__ rowsum) {
  __shared__ __align__(16) char bbuf[2][16384];
  __shared__ float colaccum[256];

  int g = blockIdx.x;  // natural order: round-robin dispatch balances XCDs

  // decode (P, c): band P has ceil((128-2P)/4) chunks of 256 cols
  int P = 0, off = 0;
  for (;;) {
    int nb = (131 - 2 * P) >> 2;
    if (g < off + nb) break;
    off += nb;
    ++P;
  }
  int c = g - off;
  const int J0 = 4 * P + 8 * c;                       // first 32-col tile index
  int ntt = 2 * (128 - 2 * P - 4 * c); if (ntt > 8) ntt = 8;  // 32-col tiles this block

  const int tid = threadIdx.x;
  const int lane = tid & 63, w = tid >> 6;
  const int lr = lane & 15, hi2 = lane >> 4;
  const char* zb = (const char*)zn8;
  const int arow0 = P * 128;

  if (tid < 256) colaccum[tid] = 0.f;

  // ---- A panel: 32 rows/wave, full K, direct global->regs (one time) ----
  long2v aR[2][8];  // 64 VGPR: row = arow0 + w*32 + m*16 + lr, k-window hi2*16 + p*64
#pragma unroll
  for (int m = 0; m < 2; ++m) {
    const char* rowp = zb + (size_t)(arow0 + (w << 5) + (m << 4) + lr) * DD + hi2 * 16;
#pragma unroll
    for (int p = 0; p < 8; ++p)
      aR[m][p] = *(const long2v*)(rowp + p * 64);
  }
  asm volatile("s_waitcnt vmcnt(0)" ::: "memory");  // A in regs; vm queue empty
  __builtin_amdgcn_sched_barrier(0);

  // stage geometry: 32-col x 512B panel -> 16KB; 4 x 16B per thread;
  // linear LDS dest, inverse-swizzled global source (XOR cancels on read)
  int srow[4], scol[4];
#pragma unroll
  for (int cc = 0; cc < 4; ++cc) {
    int lo2 = cc * 4096 + tid * 16;
    srow[cc] = lo2 >> 9;                             // col index 0..31
    scol[cc] = (lo2 & 511) ^ ((srow[cc] & 15) << 4);
  }

#define STAGE(bufp, colbase) do {                                                        \
    _Pragma("unroll")                                                                    \
    for (int cc = 0; cc < 4; ++cc) {                                                     \
      const char* _s = zb + (size_t)((colbase) + srow[cc]) * DD + scol[cc];              \
      __builtin_amdgcn_global_load_lds((__attribute__((address_space(1))) void*)_s,      \
          (__attribute__((address_space(3))) void*)((bufp) + cc * 4096 + (w << 10)),     \
          16, 0, 0);                                                                     \
    }                                                                                    \
  } while (0)

  float rowacc[2][4];
#pragma unroll
  for (int m = 0; m < 2; ++m)
#pragma unroll
    for (int r = 0; r < 4; ++r) rowacc[m][r] = 0.f;

  const float Cc = 2.88539008177792681f;
  const int sz = lr << 4;  // read-side XOR (col&15 == lr for both n-tiles)

  STAGE((char*)bbuf[0], J0 * 32);  // prologue: tile 0 in flight

  for (int t = 0; t < ntt; ++t) {
    if (t + 1 < ntt) {
      STAGE((char*)bbuf[(t + 1) & 1], (J0 + t + 1) * 32);  // next tile in flight
      asm volatile("s_waitcnt vmcnt(4)" ::: "memory");      // tile t landed
    } else {
      asm volatile("s_waitcnt vmcnt(0)" ::: "memory");
    }
    __builtin_amdgcn_sched_barrier(0);
    __builtin_amdgcn_s_barrier();  // b1: tile t visible to all waves

    const char* bb = (const char*)bbuf[t & 1];
    float4v acc[2][2];
#pragma unroll
    for (int m = 0; m < 2; ++m)
#pragma unroll
      for (int n = 0; n < 2; ++n) acc[m][n] = {0.f, 0.f, 0.f, 0.f};

#pragma unroll
    for (int n = 0; n < 2; ++n) {
      long2v bR[8];
      const char* colp = bb + ((n << 4) + lr) * DD;
#pragma unroll
      for (int p = 0; p < 8; ++p)
        bR[p] = *(const long2v*)(colp + ((p * 64 + hi2 * 16) ^ sz));
#pragma unroll
      for (int p = 0; p < 8; ++p)
#pragma unroll
        for (int m = 0; m < 2; ++m) {
          acc[m][n] = __builtin_amdgcn_mfma_f32_16x16x32_fp8_fp8(aR[m][p][0], bR[p][0], acc[m][n], 0, 0, 0);
          acc[m][n] = __builtin_amdgcn_mfma_f32_16x16x32_fp8_fp8(aR[m][p][1], bR[p][1], acc[m][n], 0, 0, 0);
        }
    }

    // epilogue tile t: e = exp(2*dot - 2) = exp2(C*dot - C)
    // D layout: row = w*32 + m*16 + hi2*4 + r, col = (J0+t)*32 + n*16 + lr
    float colp2[2] = {0.f, 0.f};
#pragma unroll
    for (int m = 0; m < 2; ++m)
#pragma unroll
      for (int n = 0; n < 2; ++n)
#pragma unroll
        for (int r = 0; r < 4; ++r) {
          float e = exp2f(fmaf(acc[m][n][r], Cc, -Cc));
          rowacc[m][r] += e;
          colp2[n] += e;
        }
    if ((J0 + t) >= 4 * P + 4) {  // mirror col-sums (strictly above the diagonal block)
#pragma unroll
      for (int n = 0; n < 2; ++n) {
        float v = colp2[n];
        v += __shfl_xor(v, 16);
        v += __shfl_xor(v, 32);
        if (hi2 == 0) atomicAdd(&colaccum[(t << 5) + (n << 4) + lr], v);  // ds_add
      }
    }
    __builtin_amdgcn_s_barrier();  // b2: all waves' reads of buf[t&1] consumed
  }
#undef STAGE

  // row atomics: one per row per block (128 rows)
#pragma unroll
  for (int m = 0; m < 2; ++m)
#pragma unroll
    for (int r = 0; r < 4; ++r) {
      float v = rowacc[m][r];
      v += __shfl_xor(v, 1);
      v += __shfl_xor(v, 2);
      v += __shfl_xor(v, 4);
      v += __shfl_xor(v, 8);
      if (lr == 0)
        atomicAdd(&rowsum[arow0 + (w << 5) + (m << 4) + (hi2 << 2) + r], v);
    }

  // col mirror flush: once per block (skip the 128 diagonal cols when c == 0)
  __syncthreads();  // lgkmcnt(0) drain: all ds_adds visible
  for (int idx = tid + (c == 0 ? 128 : 0); idx < ntt * 32; idx += 256)
    atomicAdd(&rowsum[J0 * 32 + idx], colaccum[idx]);
}

// ---------- finalize: loss = (sum(2 + log rowsum) - sum tpart) / 8192 ----------
__global__ __launch_bounds__(1024) void k_finalize(const float* __restrict__ rowsum,
                                                   const float* __restrict__ tpart,
                                                   float* __restrict__ out) {
  int t = threadIdx.x;
  float acc = 0.f;
  for (int i = t; i < N2; i += 1024) acc += 2.0f + logf(rowsum[i]);
  for (int i = t; i < B_ROWS; i += 1024) acc -= tpart[i];
#pragma unroll
  for (int o = 32; o; o >>= 1) acc += __shfl_down(acc, o, 64);
  __shared__ float wsum[16];
  if ((t & 63) == 0) wsum[t >> 6] = acc;
  __syncthreads();
  if (t == 0) {
    float s = 0.f;
#pragma unroll
    for (int k = 0; k < 16; ++k) s += wsum[k];
    out[0] = s * (1.0f / (float)N2);
  }
}

extern "C" void kernel_launch(void* const* d_in, const int* in_sizes, int n_in,
                              void* d_out, int out_size, void* d_ws, size_t ws_size,
                              hipStream_t stream) {
  const float* f1 = (const float*)d_in[0];
  const float* f2 = (const float*)d_in[1];
  float* out = (float*)d_out;
  char* ws = (char*)d_ws;

  unsigned char* zn8 = (unsigned char*)ws;               // 8192*512 = 4 MB fp8
  float* rowsum = (float*)(ws + (size_t)N2 * DD);        // 32 KB
  float* tpart = rowsum + N2;                            // 16 KB

  k_norm_tgt<<<B_ROWS / 4, 256, 0, stream>>>(f1, f2, zn8, tpart, rowsum);
  k_gemm_expsum<<<NBLK, 256, 0, stream>>>(zn8, rowsum);
  k_finalize<<<1, 1024, 0, stream>>>(rowsum, tpart, out);
}

// Round 19
// 65.938 us; speedup vs baseline: 1.1621x; 1.1621x over previous
//
#include <hip/hip_runtime.h>
#include <hip/hip_bf16.h>

#define B_ROWS 4096
#define N2 8192
#define DD 512
#define NTILE 2112   // sum over P=0..31 of (128-4P)
#define NBLK 512     // exactly 2 blocks/CU

typedef __attribute__((ext_vector_type(4))) float float4v;
typedef __attribute__((ext_vector_type(2))) long long2v;

#define AS1 __attribute__((address_space(1)))
#define AS3 __attribute__((address_space(3)))

// ---------- normalize + targets + rowsum-zero, one wave per row-pair ----------
__global__ __launch_bounds__(256) void k_norm_tgt(const float* __restrict__ f1,
                                                  const float* __restrict__ f2,
                                                  unsigned char* __restrict__ zn8,
                                                  float* __restrict__ tpart,
                                                  float* __restrict__ rowsum) {
  int w = threadIdx.x >> 6, lane = threadIdx.x & 63;
  int j = blockIdx.x * 4 + w;  // pair index 0..4095
  const float4* s1 = (const float4*)(f1 + (size_t)j * DD);
  const float4* s2 = (const float4*)(f2 + (size_t)j * DD);
  float4 a0 = s1[lane * 2], a1 = s1[lane * 2 + 1];
  float4 b0 = s2[lane * 2], b1 = s2[lane * 2 + 1];
  float ss1 = a0.x * a0.x + a0.y * a0.y + a0.z * a0.z + a0.w * a0.w +
              a1.x * a1.x + a1.y * a1.y + a1.z * a1.z + a1.w * a1.w;
  float ss2 = b0.x * b0.x + b0.y * b0.y + b0.z * b0.z + b0.w * b0.w +
              b1.x * b1.x + b1.y * b1.y + b1.z * b1.z + b1.w * b1.w;
  float ab = a0.x * b0.x + a0.y * b0.y + a0.z * b0.z + a0.w * b0.w +
             a1.x * b1.x + a1.y * b1.y + a1.z * b1.z + a1.w * b1.w;
#pragma unroll
  for (int o = 1; o < 64; o <<= 1) {
    ss1 += __shfl_xor(ss1, o, 64);
    ss2 += __shfl_xor(ss2, o, 64);
    ab += __shfl_xor(ab, o, 64);
  }
  float inv1 = 1.0f / fmaxf(sqrtf(ss1), 1e-8f);
  float inv2 = 1.0f / fmaxf(sqrtf(ss2), 1e-8f);

  uint2 q;
  int lo = __builtin_amdgcn_cvt_pk_fp8_f32(a0.x * inv1, a0.y * inv1, 0, false);
  lo = __builtin_amdgcn_cvt_pk_fp8_f32(a0.z * inv1, a0.w * inv1, lo, true);
  q.x = (unsigned int)lo;
  lo = __builtin_amdgcn_cvt_pk_fp8_f32(a1.x * inv1, a1.y * inv1, 0, false);
  lo = __builtin_amdgcn_cvt_pk_fp8_f32(a1.z * inv1, a1.w * inv1, lo, true);
  q.y = (unsigned int)lo;
  ((uint2*)(zn8 + (size_t)j * DD))[lane] = q;

  lo = __builtin_amdgcn_cvt_pk_fp8_f32(b0.x * inv2, b0.y * inv2, 0, false);
  lo = __builtin_amdgcn_cvt_pk_fp8_f32(b0.z * inv2, b0.w * inv2, lo, true);
  q.x = (unsigned int)lo;
  lo = __builtin_amdgcn_cvt_pk_fp8_f32(b1.x * inv2, b1.y * inv2, 0, false);
  lo = __builtin_amdgcn_cvt_pk_fp8_f32(b1.z * inv2, b1.w * inv2, lo, true);
  q.y = (unsigned int)lo;
  ((uint2*)(zn8 + (size_t)(B_ROWS + j) * DD))[lane] = q;

  if (lane == 0) tpart[j] = 2.0f + 2.0f * ab * inv1 * inv2;
  if (threadIdx.x < 8) rowsum[blockIdx.x * 8 + threadIdx.x] = 0.f;
}

// ---------- main: 256-row persistent-A bands, fp8 GEMM + exp-rowsum ----------
// 512 blocks (= residency), static tile partition s(b)=(33b)>>3 over 2112
// tiles. Wave holds 64 A-rows x 512 K in regs (aR[4][8]); per tile a 64-col
// B-panel is dbuf-staged (counted vmcnt(8), lgkm-only barriers). Per-n
// accumulator (accm[4]) keeps VGPR ~210. Mirror col-sums for j >= 4P+4.
__global__ __launch_bounds__(256, 2) void k_gemm_expsum(const unsigned char* __restrict__ zn8,
                                                        float* __restrict__ rowsum) {
  __shared__ __align__(16) char bbuf[2][32768];
  __shared__ float colaccum[2][64];

  const int tid = threadIdx.x;
  const int lane = tid & 63, w = tid >> 6;
  const int lr = lane & 15, hi2 = lane >> 4;
  const char* zb = (const char*)zn8;
  const float Cc = 2.88539008177792681f;

  const int t0 = (33 * blockIdx.x) >> 3;
  const int t1 = (33 * (blockIdx.x + 1)) >> 3;

  if (tid < 128) ((float*)colaccum)[tid] = 0.f;

#define DECODE(T, Pv, jv) do {                                     \
    int _P = 0;                                                    \
    while (2 * (_P + 1) * (64 - _P) <= (T)) ++_P;                  \
    (Pv) = _P;                                                     \
    (jv) = 4 * _P + ((T) - 2 * _P * (65 - _P));                    \
  } while (0)

#define STAGE(bufp, vecbase) do {                                                        \
    _Pragma("unroll")                                                                    \
    for (int cc = 0; cc < 8; ++cc) {                                                     \
      int srw = cc * 8 + (w << 1) + (lane >> 5);                                         \
      int scl = ((lane & 31) << 4) ^ ((srw & 15) << 4);                                  \
      const char* _s = zb + (size_t)((vecbase) + srw) * DD + scl;                        \
      __builtin_amdgcn_global_load_lds((AS1 void*)_s,                                    \
          (AS3 void*)((bufp) + cc * 4096 + (w << 10)), 16, 0, 0);                        \
    }                                                                                    \
  } while (0)

  long2v aR[4][8];      // 128 VGPR: rows band*256 + w*64 + m*16 + lr
  float rowacc[4][4];
#pragma unroll
  for (int m = 0; m < 4; ++m)
#pragma unroll
    for (int r = 0; r < 4; ++r) rowacc[m][r] = 0.f;

#define LOAD_A(Pban) do {                                                                \
    _Pragma("unroll")                                                                    \
    for (int m = 0; m < 4; ++m) {                                                        \
      const char* rowp = zb + (size_t)(((Pban) << 8) + (w << 6) + (m << 4) + lr) * DD + hi2 * 16; \
      _Pragma("unroll")                                                                  \
      for (int p = 0; p < 8; ++p) aR[m][p] = *(const long2v*)(rowp + p * 64);            \
    }                                                                                    \
    asm volatile("s_waitcnt vmcnt(0)" ::: "memory");                                     \
    __builtin_amdgcn_sched_barrier(0);                                                   \
  } while (0)

#define FLUSH_ROWS(Pban) do {                                                            \
    _Pragma("unroll")                                                                    \
    for (int m = 0; m < 4; ++m)                                                          \
    _Pragma("unroll")                                                                    \
      for (int r = 0; r < 4; ++r) {                                                      \
        float v = rowacc[m][r];                                                          \
        v += __shfl_xor(v, 1); v += __shfl_xor(v, 2);                                    \
        v += __shfl_xor(v, 4); v += __shfl_xor(v, 8);                                    \
        if (lr == 0)                                                                     \
          atomicAdd(&rowsum[((Pban) << 8) + (w << 6) + (m << 4) + (hi2 << 2) + r], v);   \
        rowacc[m][r] = 0.f;                                                              \
      }                                                                                  \
  } while (0)

  // prologue: decode first tile, stage it, full-drain barrier (also covers colaccum zero)
  int Pt, jt;
  DECODE(t0, Pt, jt);
  STAGE((char*)bbuf[0], jt * 64);
  int curP = -1;
  __syncthreads();

  int cur = 0;
  for (int t = t0; t < t1; ++t) {
    int Pn = 0, jn = 0;
    if (t + 1 < t1) {
      DECODE(t + 1, Pn, jn);
      STAGE((char*)bbuf[cur ^ 1], jn * 64);   // next tile in flight across barriers
    }
    if (Pt != curP) {                          // band change: flush rows, reload A (rare)
      if (curP >= 0) FLUSH_ROWS(curP);
      LOAD_A(Pt);                              // drains vmcnt(0) (one-time overlap loss)
      curP = Pt;
    }
    if (t + 1 < t1) {
      asm volatile("s_waitcnt vmcnt(8)" ::: "memory");  // tile t resident; t+1 in flight
    } else {
      asm volatile("s_waitcnt vmcnt(0)" ::: "memory");
    }
    __builtin_amdgcn_sched_barrier(0);
    __builtin_amdgcn_s_barrier();              // b1: panel t visible

    const char* bb = (const char*)bbuf[cur];
    const bool mir = (jt >= 4 * Pt + 4);
    const int sz = lr << 4;

#pragma unroll
    for (int n = 0; n < 4; ++n) {
      long2v bR[8];
      const char* colp = bb + (((n << 4) + lr) << 9);
#pragma unroll
      for (int p = 0; p < 8; ++p)
        bR[p] = *(const long2v*)(colp + ((p * 64 + hi2 * 16) ^ sz));

      float4v accm[4];
#pragma unroll
      for (int m = 0; m < 4; ++m) accm[m] = {0.f, 0.f, 0.f, 0.f};
#pragma unroll
      for (int p = 0; p < 8; ++p)
#pragma unroll
        for (int m = 0; m < 4; ++m) {
          accm[m] = __builtin_amdgcn_mfma_f32_16x16x32_fp8_fp8(aR[m][p][0], bR[p][0], accm[m], 0, 0, 0);
          accm[m] = __builtin_amdgcn_mfma_f32_16x16x32_fp8_fp8(aR[m][p][1], bR[p][1], accm[m], 0, 0, 0);
        }

      // per-n epilogue: e = exp(2*dot - 2); rows w*64+m*16+hi2*4+r, col n*16+lr
      float colpn = 0.f;
#pragma unroll
      for (int m = 0; m < 4; ++m)
#pragma unroll
        for (int r = 0; r < 4; ++r) {
          float e = exp2f(fmaf(accm[m][r], Cc, -Cc));
          rowacc[m][r] += e;
          colpn += e;
        }
      if (mir) {
        colpn += __shfl_xor(colpn, 16);
        colpn += __shfl_xor(colpn, 32);
        if (hi2 == 0) atomicAdd(&colaccum[cur][(n << 4) + lr], colpn);  // ds_add
      }
    }

    // end-of-tile: drain LDS ops only (keep stage t+1 in flight), barrier
    asm volatile("s_waitcnt lgkmcnt(0)" ::: "memory");
    __builtin_amdgcn_sched_barrier(0);
    __builtin_amdgcn_s_barrier();              // b2: buf[cur] reads + ds_adds done

    if (mir && w == 0) {                       // wave0 flushes this tile's mirror cols
      float v = colaccum[cur][lane];
      if (v != 0.f) atomicAdd(&rowsum[jt * 64 + lane], v);
      colaccum[cur][lane] = 0.f;
    }

    Pt = Pn; jt = jn; cur ^= 1;
  }

  FLUSH_ROWS(curP);

#undef DECODE
#undef STAGE
#undef LOAD_A
#undef FLUSH_ROWS
}

// ---------- finalize: loss = (sum(2 + log rowsum) - sum tpart) / 8192 ----------
__global__ __launch_bounds__(1024) void k_finalize(const float* __restrict__ rowsum,
                                                   const float* __restrict__ tpart,
                                                   float* __restrict__ out) {
  int t = threadIdx.x;
  float acc = 0.f;
  for (int i = t; i < N2; i += 1024) acc += 2.0f + logf(rowsum[i]);
  for (int i = t; i < B_ROWS; i += 1024) acc -= tpart[i];
#pragma unroll
  for (int o = 32; o; o >>= 1) acc += __shfl_down(acc, o, 64);
  __shared__ float wsum[16];
  if ((t & 63) == 0) wsum[t >> 6] = acc;
  __syncthreads();
  if (t == 0) {
    float s = 0.f;
#pragma unroll
    for (int k = 0; k < 16; ++k) s += wsum[k];
    out[0] = s * (1.0f / (float)N2);
  }
}

extern "C" void kernel_launch(void* const* d_in, const int* in_sizes, int n_in,
                              void* d_out, int out_size, void* d_ws, size_t ws_size,
                              hipStream_t stream) {
  const float* f1 = (const float*)d_in[0];
  const float* f2 = (const float*)d_in[1];
  float* out = (float*)d_out;
  char* ws = (char*)d_ws;

  unsigned char* zn8 = (unsigned char*)ws;               // 8192*512 = 4 MB fp8
  float* rowsum = (float*)(ws + (size_t)N2 * DD);        // 32 KB
  float* tpart = rowsum + N2;                            // 16 KB

  k_norm_tgt<<<B_ROWS / 4, 256, 0, stream>>>(f1, f2, zn8, tpart, rowsum);
  k_gemm_expsum<<<NBLK, 256, 0, stream>>>(zn8, rowsum);
  k_finalize<<<1, 1024, 0, stream>>>(rowsum, tpart, out);
}